// Round 14
// baseline (3043.778 us; speedup 1.0000x reference)
//
#include <hip/hip_runtime.h>

constexpr int B_ = 64, I_ = 256, H_ = 512, T_ = 512;
constexpr int BH_ = B_ * H_;

// d_ws layout: [0,256KB) hbuf ping-pong (tagged h) | [512KB,+33.5MB) xT
constexpr size_t WS_XT_OFF = 524288;

typedef float f32x4 __attribute__((ext_vector_type(4)));

__device__ __forceinline__ float sigm(float v) { return 1.0f / (1.0f + __expf(-v)); }

// x (B,I,T) -> xT (T,B,I), one-time
__global__ __launch_bounds__(256)
void transpose_x(const float* __restrict__ x, float* __restrict__ xT)
{
    __shared__ float tile[32][33];
    const int b  = blockIdx.z;
    const int i0 = blockIdx.y << 5;
    const int t0 = blockIdx.x << 5;
    const int lt = threadIdx.x;      // 0..31
    const int li = threadIdx.y;      // 0..7
#pragma unroll
    for (int r = 0; r < 4; ++r) {
        int i = li + (r << 3);
        tile[i][lt] = x[((size_t)b * I_ + (i0 + i)) * T_ + (t0 + lt)];
    }
    __syncthreads();
#pragma unroll
    for (int r = 0; r < 4; ++r) {
        int tt = li + (r << 3);
        xT[((size_t)(t0 + tt) * B_ + b) * I_ + (i0 + lt)] = tile[lt][tt];
    }
}

__global__ __launch_bounds__(512, 1)
void lstm_fused(const float* __restrict__ x,
                const float* __restrict__ xT,     // nullptr -> strided fallback
                const float* __restrict__ Wih,
                const float* __restrict__ Whh,
                const float* __restrict__ bih,
                const float* __restrict__ bhh,
                const float* __restrict__ h0,
                const float* __restrict__ c0,
                float* __restrict__ out,
                float* __restrict__ hbuf)
{
    // 64 KiB static LDS, all double-buffered or wave-private (1 barrier/step):
    __shared__ float redW[2][8][512];   // per-wave reduced partials [buf][wave][(bq*16+jl)*4+g]
                                        //   tail [448..512) of rows 0-1 doubles as hsh
    __shared__ float actx[2][8][256];   // x slab dbuf
    __shared__ float acth[8][512];      // h staging (strictly wave-private windows)

    const int tid  = threadIdx.x;
    const int wv   = tid >> 6;
    const int lane = tid & 63;
    const int jl   = lane & 15;            // j within block's 16
    const int slq  = lane >> 4;            // 0..3
    const int sl   = (wv << 2) + slq;      // k-slice 0..31 == producer jt for h-part

    const int blk = blockIdx.x;
    const int bt  = blk >> 5;              // team (b-tile)
    const int jt  = blk & 31;              // j-block
    const int b0  = bt << 3;
    const int j0  = jt << 4;

    // ---- weights in registers: x-part k=[sl*8,+8), h-part k=[sl*16,+16) ----
    const int j = j0 + jl;
    float w_x[4][8];
    float w_h[4][16];
#pragma unroll
    for (int g = 0; g < 4; ++g) {
        const size_t row = (size_t)(g * H_ + j);
#pragma unroll
        for (int kk = 0; kk < 8; ++kk)  w_x[g][kk] = Wih[row * I_ + (sl << 3) + kk];
#pragma unroll
        for (int kk = 0; kk < 16; ++kk) w_h[g][kk] = Whh[row * H_ + (sl << 4) + kk];
    }

    // finalizer (tid<128) per-(b,j) state
    const int fb = b0 + (tid >> 4);
    const int fj = j0 + (tid & 15);
    float c = 0.f;
    f32x4 bias4 = {0.f, 0.f, 0.f, 0.f};
    if (tid < 128) {
        c = c0[(size_t)fb * H_ + fj];
#pragma unroll
        for (int g = 0; g < 4; ++g) bias4[g] = bih[g * H_ + fj] + bhh[g * H_ + fj];
    }

    float* enc = out + BH_;

    // h-stage role within 16-lane slice group
    const int hs_bq  = jl >> 1;                        // batch 0..7
    const int hs_off = (sl << 4) + ((jl & 1) << 3);    // k-offset in h row

    // ---- prologue: x(0) committed, x(1) prefetched ----
    float4 xv; float xr[4];
    if (xT) {
        float4 v0 = ((const float4*)(xT + (size_t)b0 * I_))[tid];
        *(float4*)(&actx[0][tid >> 6][(tid & 63) << 2]) = v0;
        xv = ((const float4*)(xT + (size_t)B_ * I_ + (size_t)b0 * I_))[tid];
    } else {
#pragma unroll
        for (int r = 0; r < 4; ++r) {
            int flat = tid + (r << 9);
            actx[0][flat >> 8][flat & 255] =
                x[((size_t)(b0 + (flat >> 8)) * I_ + (flat & 255)) * T_ + 0];
        }
#pragma unroll
        for (int r = 0; r < 4; ++r) {
            int flat = tid + (r << 9);
            xr[r] = x[((size_t)(b0 + (flat >> 8)) * I_ + (flat & 255)) * T_ + 1];
        }
    }
    __syncthreads();

    for (int t = 0; t < T_; ++t) {
        // ---- (b) FMA x-part from actx[t&1] ----
        f32x4 r4[8];
#pragma unroll
        for (int bq = 0; bq < 8; ++bq) {
            const f32x4* ap = (const f32x4*)(&actx[t & 1][bq][sl << 3]);
            float s0 = 0.f, s1 = 0.f, s2 = 0.f, s3 = 0.f;
#pragma unroll
            for (int q2 = 0; q2 < 2; ++q2) {
                f32x4 a = ap[q2];
#pragma unroll
                for (int e = 0; e < 4; ++e) {
                    const float av = a[e];
                    const int kk = (q2 << 2) + e;
                    s0 += av * w_x[0][kk]; s1 += av * w_x[1][kk];
                    s2 += av * w_x[2][kk]; s3 += av * w_x[3][kk];
                }
            }
            r4[bq] = (f32x4){s0, s1, s2, s3};
        }

        // ---- (e) h(t-1): per-thread TAGGED-DATA poll of own slice, stage to LDS ----
        {
            f32x4 v0, v1;
            if (t == 0) {
                const float* src = h0 + (size_t)(b0 + hs_bq) * H_ + hs_off;
                v0 = *(const f32x4*)src;
                v1 = *(const f32x4*)(src + 4);
            } else {
                const float* src = hbuf + (size_t)((t - 1) & 1) * BH_
                                 + (size_t)(b0 + hs_bq) * H_ + hs_off;
                const float Kc = 2.0f + 2.0f * (float)(((t - 1) >> 1) & 1);
                for (unsigned it = 0; it < 32768u; ++it) {
                    asm volatile("global_load_dwordx4 %0, %2, off sc0 sc1\n\t"
                                 "global_load_dwordx4 %1, %3, off sc0 sc1\n\t"
                                 "s_waitcnt vmcnt(0)"
                                 : "=&v"(v0), "=&v"(v1) : "v"(src), "v"(src + 4) : "memory");
                    bool ok = true;
#pragma unroll
                    for (int e = 0; e < 4; ++e) {
                        ok = ok && (fabsf(v0[e] - Kc) < 0.75f);
                        ok = ok && (fabsf(v1[e] - Kc) < 0.75f);
                    }
                    if (ok) break;
                    __builtin_amdgcn_s_sleep(1);
                }
                v0 = (v0 - Kc) * 2.0f;
                v1 = (v1 - Kc) * 2.0f;
            }
            *(f32x4*)(&acth[hs_bq][hs_off])     = v0;
            *(f32x4*)(&acth[hs_bq][hs_off + 4]) = v1;
        }

        // ---- (f) FMA h-part (wave-private acth window; compiler handles lgkmcnt) ----
#pragma unroll
        for (int bq = 0; bq < 8; ++bq) {
            const f32x4* ap = (const f32x4*)(&acth[bq][sl << 4]);
            float s0 = 0.f, s1 = 0.f, s2 = 0.f, s3 = 0.f;
#pragma unroll
            for (int q4 = 0; q4 < 4; ++q4) {
                f32x4 a = ap[q4];
#pragma unroll
                for (int e = 0; e < 4; ++e) {
                    const float av = a[e];
                    const int kk = (q4 << 2) + e;
                    s0 += av * w_h[0][kk]; s1 += av * w_h[1][kk];
                    s2 += av * w_h[2][kk]; s3 += av * w_h[3][kk];
                }
            }
            r4[bq] += (f32x4){s0, s1, s2, s3};
        }

        // ---- in-wave butterfly over the wave's 4 k-slices ----
#pragma unroll
        for (int bq = 0; bq < 8; ++bq) {
#pragma unroll
            for (int e = 0; e < 4; ++e) {
                float a = r4[bq][e];
                a += __shfl_xor(a, 16);
                a += __shfl_xor(a, 32);
                r4[bq][e] = a;
            }
        }
        // lanes slq==0 write the wave's reduced row
        if (slq == 0) {
            float* row = &redW[t & 1][wv][0];
#pragma unroll
            for (int bq = 0; bq < 8; ++bq)
                *(f32x4*)(row + (bq << 6) + (jl << 2)) = r4[bq];
        }

        // ---- commit x(t+1) to actx[(t+1)&1]; prefetch x(t+2) ----
        if (t + 1 < T_) {
            if (xT) {
                *(float4*)(&actx[(t + 1) & 1][tid >> 6][(tid & 63) << 2]) = xv;
                if (t + 2 < T_)
                    xv = ((const float4*)(xT + (size_t)(t + 2) * B_ * I_
                                             + (size_t)b0 * I_))[tid];
            } else {
#pragma unroll
                for (int r = 0; r < 4; ++r) {
                    int flat = tid + (r << 9);
                    actx[(t + 1) & 1][flat >> 8][flat & 255] = xr[r];
                }
                if (t + 2 < T_) {
#pragma unroll
                    for (int r = 0; r < 4; ++r) {
                        int flat = tid + (r << 9);
                        xr[r] = x[((size_t)(b0 + (flat >> 8)) * I_ + (flat & 255)) * T_
                                  + (t + 2)];
                    }
                }
            }
        }

        __syncthreads();    // the ONE barrier: redW[t&1] complete, actx[(t+1)&1] complete

        // ---- finalize (waves 0-1): gates, state, enc, tagged publish ----
        if (tid < 128) {
            f32x4 G = bias4;
#pragma unroll
            for (int w = 0; w < 8; ++w)
                G += *(const f32x4*)(&redW[t & 1][w][tid << 2]);
            float ig = sigm(G[0]), fg = sigm(G[1]), gg = tanhf(G[2]), og = sigm(G[3]);
            c = fg * c + ig * gg;
            float hv = og * tanhf(c);
            enc[((size_t)fb * H_ + fj) * T_ + t] = hv;           // plain cached store
            if (t == T_ - 1) out[(size_t)fb * H_ + fj] = hv;
            else redW[(t + 1) & 1][wv][448 + lane] = hv;         // hsh parked in next buf
        }
        if (wv < 2 && t != T_ - 1) {
            asm volatile("s_waitcnt lgkmcnt(0)" ::: "memory");   // own-wave hsh visible
            __builtin_amdgcn_sched_barrier(0);
            if (lane < 16) {
                const float Kp = 2.0f + 2.0f * (float)((t >> 1) & 1);
                f32x4 hv4 = *(const f32x4*)(&redW[(t + 1) & 1][wv]
                                            [448 + ((lane >> 2) << 4) + ((lane & 3) << 2)]);
                hv4 = hv4 * 0.5f + Kp;                           // tag-bias
                float* dst = hbuf + (size_t)(t & 1) * BH_
                           + (size_t)(b0 + (wv << 2) + (lane >> 2)) * H_
                           + j0 + ((lane & 3) << 2);
                asm volatile("global_store_dwordx4 %0, %1, off sc0 sc1"
                             :: "v"(dst), "v"(hv4) : "memory");  // fire-and-forget
            }
        }
        // WAW safety: each publisher's next-step poll loads issue s_waitcnt vmcnt(0),
        // draining these stores before the same address is written again at t+2.
    }
}

extern "C" void kernel_launch(void* const* d_in, const int* in_sizes, int n_in,
                              void* d_out, int out_size, void* d_ws, size_t ws_size,
                              hipStream_t stream)
{
    (void)in_sizes; (void)n_in; (void)out_size;
    const float* x   = (const float*)d_in[0];
    const float* Wih = (const float*)d_in[1];
    const float* Whh = (const float*)d_in[2];
    const float* bih = (const float*)d_in[3];
    const float* bhh = (const float*)d_in[4];
    const float* h0  = (const float*)d_in[5];
    const float* c0  = (const float*)d_in[6];
    float* out  = (float*)d_out;
    float* hbuf = (float*)d_ws;

    const size_t xt_bytes = (size_t)T_ * B_ * I_ * sizeof(float);
    float* xT = nullptr;
    if (ws_size >= WS_XT_OFF + xt_bytes)
        xT = (float*)((char*)d_ws + WS_XT_OFF);

    // zero hbuf every launch: stale tags from a previous replay must not validate
    hipMemsetAsync(d_ws, 0, 2 * BH_ * sizeof(float), stream);
    if (xT)
        transpose_x<<<dim3(T_ / 32, I_ / 32, B_), dim3(32, 8), 0, stream>>>(x, xT);

    void* args[] = { (void*)&x, (void*)&xT, (void*)&Wih, (void*)&Whh, (void*)&bih,
                     (void*)&bhh, (void*)&h0, (void*)&c0, (void*)&out, (void*)&hbuf };
    hipLaunchCooperativeKernel((void*)lstm_fused, dim3(256), dim3(512), args, 0, stream);
}

// Round 17
// 2360.663 us; speedup vs baseline: 1.2894x; 1.2894x over previous
//
#include <hip/hip_runtime.h>

constexpr int B_ = 64, I_ = 256, H_ = 512, T_ = 512;
constexpr int BH_ = B_ * H_;

// d_ws layout: [0,256KB) hbuf ping-pong | [256KB,+64KB) flags | [512KB,+33.5MB) xT
constexpr size_t WS_CNT_OFF = 262144;
constexpr size_t WS_XT_OFF  = 524288;
constexpr int C_FLAG = 512;     // word offset into flag zone

typedef float f32x4 __attribute__((ext_vector_type(4)));

__device__ __forceinline__ float sigm(float v) { return 1.0f / (1.0f + __expf(-v)); }

// system-scope (IF) uncached flag ops — the proven visibility path
__device__ __forceinline__ unsigned flag_load(const unsigned* p) {
    unsigned v;
    asm volatile("global_load_dword %0, %1, off sc0 sc1\n\ts_waitcnt vmcnt(0)"
                 : "=v"(v) : "v"(p) : "memory");
    return v;
}
__device__ __forceinline__ void flag_store(unsigned* p, unsigned v) {
    asm volatile("global_store_dword %0, %1, off sc0 sc1" :: "v"(p), "v"(v) : "memory");
}

// x (B,I,T) -> xT (T,B,I), one-time
__global__ __launch_bounds__(256)
void transpose_x(const float* __restrict__ x, float* __restrict__ xT)
{
    __shared__ float tile[32][33];
    const int b  = blockIdx.z;
    const int i0 = blockIdx.y << 5;
    const int t0 = blockIdx.x << 5;
    const int lt = threadIdx.x;      // 0..31
    const int li = threadIdx.y;      // 0..7
#pragma unroll
    for (int r = 0; r < 4; ++r) {
        int i = li + (r << 3);
        tile[i][lt] = x[((size_t)b * I_ + (i0 + i)) * T_ + (t0 + lt)];
    }
    __syncthreads();
#pragma unroll
    for (int r = 0; r < 4; ++r) {
        int tt = li + (r << 3);
        xT[((size_t)(t0 + tt) * B_ + b) * I_ + (i0 + lt)] = tile[lt][tt];
    }
}

// ============================================================================
// SMALL kernel: 512 blocks x 256 threads, 2 blocks/CU (TLP hides the IF chain)
// ============================================================================
__global__ __launch_bounds__(256, 2)
void lstm_small(const float* __restrict__ x,
                const float* __restrict__ xT,
                const float* __restrict__ Wih,
                const float* __restrict__ Whh,
                const float* __restrict__ bih,
                const float* __restrict__ bhh,
                const float* __restrict__ h0,
                const float* __restrict__ c0,
                float* __restrict__ out,
                float* __restrict__ hbuf,
                unsigned* __restrict__ cnt)
{
    __shared__ float act[8][772];    // [b][ x:0..256 | h:256..768 ] (+4 pad)
    __shared__ f32x4 redW[4][64];    // per-wave reduced partials
    __shared__ float hsh[64];

    const int tid  = threadIdx.x;          // 0..255 (4 waves)
    const int wv   = tid >> 6;
    const int lane = tid & 63;
    const int jl   = lane & 7;
    const int slq  = lane >> 3;
    const int sl   = (wv << 3) | slq;      // k-slice 0..31

    const int blk = blockIdx.x;            // 512 blocks
    const int bt  = blk >> 6;              // team (blk, blk+256 -> different teams)
    const int jt8 = blk & 63;
    const int b0  = bt << 3;
    const int j0  = jt8 << 3;

    unsigned* flags  = cnt + C_FLAG + bt * 64;
    unsigned* myflag = flags + jt8;

    const int j = j0 + jl;
    float w_x[4][8];
    float w_h[4][16];
#pragma unroll
    for (int g = 0; g < 4; ++g) {
        const size_t row = (size_t)(g * H_ + j);
#pragma unroll
        for (int kk = 0; kk < 8; ++kk)  w_x[g][kk] = Wih[row * I_ + (sl << 3) + kk];
#pragma unroll
        for (int kk = 0; kk < 16; ++kk) w_h[g][kk] = Whh[row * H_ + (sl << 4) + kk];
    }

    const int fb = b0 + (tid >> 3);
    const int fj = j0 + (tid & 7);
    float c = 0.f;
    f32x4 bias4 = {0.f, 0.f, 0.f, 0.f};
    if (tid < 64) {
        c = c0[(size_t)fb * H_ + fj];
#pragma unroll
        for (int g = 0; g < 4; ++g) bias4[g] = bih[g * H_ + fj] + bhh[g * H_ + fj];
    }

    float* enc = out + BH_;
    const int rotx = (slq >> 2) & 1;
    const int roth = (slq >> 1) & 3;

    float4 xv0, xv1;
    if (xT) {
        const float4* slab = (const float4*)(xT + (size_t)b0 * I_);
        xv0 = slab[tid]; xv1 = slab[tid + 256];
    }

    for (int t = 0; t < T_; ++t) {
        // (a) commit x(t)
        if (xT) {
            const int u0 = tid, u1 = tid + 256;
            *(float4*)(&act[u0 >> 6][(u0 & 63) << 2]) = xv0;
            *(float4*)(&act[u1 >> 6][(u1 & 63) << 2]) = xv1;
        } else {
#pragma unroll
            for (int r = 0; r < 8; ++r) {
                int u = tid + (r << 8), bb = u >> 8, ii = u & 255;
                act[bb][ii] = x[((size_t)(b0 + bb) * I_ + ii) * T_ + t];
            }
        }
        __syncthreads();

        // (b) FMA x-part
        f32x4 r4[8];
#pragma unroll
        for (int bq = 0; bq < 8; ++bq) {
            const f32x4* ap = (const f32x4*)(&act[bq][sl << 3]);
            float s0 = 0.f, s1 = 0.f, s2 = 0.f, s3 = 0.f;
#pragma unroll
            for (int qi = 0; qi < 2; ++qi) {
                const int q2 = (qi + rotx) & 1;
                f32x4 a = ap[q2];
#pragma unroll
                for (int e = 0; e < 4; ++e) {
                    const float av = a[e];
                    const int kk = (q2 << 2) + e;
                    s0 += av * w_x[0][kk]; s1 += av * w_x[1][kk];
                    s2 += av * w_x[2][kk]; s3 += av * w_x[3][kk];
                }
            }
            r4[bq] = (f32x4){s0, s1, s2, s3};
        }

        // (c) prefetch x(t+1)
        if (xT && t + 1 < T_) {
            const float4* slab = (const float4*)(xT + ((size_t)(t + 1) * B_ + b0) * I_);
            xv0 = slab[tid]; xv1 = slab[tid + 256];
        }

        // (d) wave0 polls team's 64 flags (bounded)
        if (t > 0 && tid < 64) {
            const unsigned tgt = (unsigned)t;
            for (unsigned it = 0; it < (1u << 17); ++it) {
                unsigned v = flag_load(flags + tid);
                if (__all((int)(v >= tgt))) break;
                __builtin_amdgcn_s_sleep(1);
            }
        }
        __syncthreads();

        // (e) stage h(t-1)
        if (t == 0) {
#pragma unroll
            for (int r = 0; r < 4; ++r) {
                int u = tid + (r << 8), bb = u >> 7, q = u & 127;
                float4 v = ((const float4*)(h0 + (size_t)(b0 + bb) * H_))[q];
                *(float4*)(&act[bb][256 + (q << 2)]) = v;
            }
        } else {
            const float* hsrc = hbuf + (size_t)((t - 1) & 1) * BH_;
            const float* a0 = hsrc + (size_t)(b0 + ((tid)       >> 7)) * H_ + (((tid)       & 127) << 2);
            const float* a1 = hsrc + (size_t)(b0 + ((tid + 256) >> 7)) * H_ + (((tid + 256) & 127) << 2);
            const float* a2 = hsrc + (size_t)(b0 + ((tid + 512) >> 7)) * H_ + (((tid + 512) & 127) << 2);
            const float* a3 = hsrc + (size_t)(b0 + ((tid + 768) >> 7)) * H_ + (((tid + 768) & 127) << 2);
            f32x4 v0, v1, v2, v3;
            asm volatile("global_load_dwordx4 %0, %4, off sc0 sc1\n\t"
                         "global_load_dwordx4 %1, %5, off sc0 sc1\n\t"
                         "global_load_dwordx4 %2, %6, off sc0 sc1\n\t"
                         "global_load_dwordx4 %3, %7, off sc0 sc1\n\t"
                         "s_waitcnt vmcnt(0)"
                         : "=&v"(v0), "=&v"(v1), "=&v"(v2), "=&v"(v3)
                         : "v"(a0), "v"(a1), "v"(a2), "v"(a3) : "memory");
            __builtin_amdgcn_sched_barrier(0);
            *(f32x4*)(&act[(tid)       >> 7][256 + (((tid)       & 127) << 2)]) = v0;
            *(f32x4*)(&act[(tid + 256) >> 7][256 + (((tid + 256) & 127) << 2)]) = v1;
            *(f32x4*)(&act[(tid + 512) >> 7][256 + (((tid + 512) & 127) << 2)]) = v2;
            *(f32x4*)(&act[(tid + 768) >> 7][256 + (((tid + 768) & 127) << 2)]) = v3;
        }
        __syncthreads();

        // (f) FMA h-part
#pragma unroll
        for (int bq = 0; bq < 8; ++bq) {
            const f32x4* ap = (const f32x4*)(&act[bq][256 + (sl << 4)]);
            float s0 = 0.f, s1 = 0.f, s2 = 0.f, s3 = 0.f;
#pragma unroll
            for (int qi = 0; qi < 4; ++qi) {
                const int q4 = (qi + roth) & 3;
                f32x4 a = ap[q4];
#pragma unroll
                for (int e = 0; e < 4; ++e) {
                    const float av = a[e];
                    const int kk = (q4 << 2) + e;
                    s0 += av * w_h[0][kk]; s1 += av * w_h[1][kk];
                    s2 += av * w_h[2][kk]; s3 += av * w_h[3][kk];
                }
            }
            r4[bq] += (f32x4){s0, s1, s2, s3};
        }

        // (g) in-wave butterfly over the wave's 8 k-slices
#pragma unroll
        for (int bq = 0; bq < 8; ++bq) {
#pragma unroll
            for (int e = 0; e < 4; ++e) {
                float a = r4[bq][e];
                a += __shfl_xor(a, 8);
                a += __shfl_xor(a, 16);
                a += __shfl_xor(a, 32);
                r4[bq][e] = a;
            }
        }
        if (slq == 0) {
#pragma unroll
            for (int bq = 0; bq < 8; ++bq) redW[wv][(bq << 3) | jl] = r4[bq];
        }
        __syncthreads();

        // (h) finalize
        if (tid < 64) {
            f32x4 G = redW[0][tid] + redW[1][tid] + redW[2][tid] + redW[3][tid] + bias4;
            float ig = sigm(G[0]), fg = sigm(G[1]), gg = tanhf(G[2]), og = sigm(G[3]);
            c = fg * c + ig * gg;
            float hv = og * tanhf(c);
            hsh[tid] = hv;
            enc[((size_t)fb * H_ + fj) * T_ + t] = hv;
            if (t == T_ - 1) out[(size_t)fb * H_ + fj] = hv;
        }
        __syncthreads();

        // (i) publish + flag
        if (t != T_ - 1) {
            if (tid < 16) {
                f32x4 v = *(const f32x4*)(&hsh[tid << 2]);
                float* dst = hbuf + (size_t)(t & 1) * BH_
                           + (size_t)(b0 + (tid >> 1)) * H_ + j0 + ((tid & 1) << 2);
                asm volatile("global_store_dwordx4 %0, %1, off sc0 sc1"
                             :: "v"(dst), "v"(v) : "memory");
            }
            if (wv == 0) {
                asm volatile("s_waitcnt vmcnt(0)" ::: "memory");
                if (tid == 0) flag_store(myflag, (unsigned)(t + 1));
            }
        }
    }
}

// ============================================================================
// BIG kernel: 256 blocks x 512 threads — round-13 fallback (proven 2366 us)
// ============================================================================
__global__ __launch_bounds__(512, 1)
void lstm_big(const float* __restrict__ x,
              const float* __restrict__ xT,
              const float* __restrict__ Wih,
              const float* __restrict__ Whh,
              const float* __restrict__ bih,
              const float* __restrict__ bhh,
              const float* __restrict__ h0,
              const float* __restrict__ c0,
              float* __restrict__ out,
              float* __restrict__ hbuf,
              unsigned* __restrict__ cnt)
{
    __shared__ char smem[59264];
    f32x4* redA = (f32x4*)smem;
    f32x4* red2 = (f32x4*)smem;
    float* act  = (float*)(smem + 34048);
    float* hsh  = (float*)(smem + 34048 + 24704);

    const int tid  = threadIdx.x;
    const int wv   = tid >> 6;
    const int lane = tid & 63;
    const int jl   = lane & 15;
    const int sl   = wv * 4 + (lane >> 4);

    const int blk = blockIdx.x;
    const int bt  = blk >> 5;
    const int jt  = blk & 31;
    const int b0  = bt << 3;
    const int j0  = jt << 4;
    unsigned* flags  = cnt + C_FLAG + 1024 + bt * 512;   // 64B stride per producer
    unsigned* myflag = flags + jt * 16;
    const unsigned* pflag = flags + sl * 16;

    const int j = j0 + jl;
    float w_x[4][8];
    float w_h[4][16];
#pragma unroll
    for (int g = 0; g < 4; ++g) {
        const size_t row = (size_t)(g * H_ + j);
#pragma unroll
        for (int kk = 0; kk < 8; ++kk)  w_x[g][kk] = Wih[row * I_ + (sl << 3) + kk];
#pragma unroll
        for (int kk = 0; kk < 16; ++kk) w_h[g][kk] = Whh[row * H_ + (sl << 4) + kk];
    }

    const int fb = b0 + (tid >> 4);
    const int fj = j0 + (tid & 15);
    float c = 0.f;
    f32x4 bias4 = {0.f, 0.f, 0.f, 0.f};
    if (tid < 128) {
        c = c0[(size_t)fb * H_ + fj];
#pragma unroll
        for (int g = 0; g < 4; ++g) bias4[g] = bih[g * H_ + fj] + bhh[g * H_ + fj];
    }

    float* enc = out + BH_;
    const int pr = tid & 127;
    const int qq = tid >> 7;
    const int hs_bq  = jl >> 1;
    const int hs_off = (sl << 4) + ((jl & 1) << 3);

    float4 xv;
    if (xT) xv = ((const float4*)(xT + (size_t)b0 * I_))[tid];

    for (int t = 0; t < T_; ++t) {
        if (xT) {
            *(float4*)(act + (tid >> 6) * 772 + ((tid & 63) << 2)) = xv;
        } else {
#pragma unroll
            for (int r = 0; r < 4; ++r) {
                int flat = tid + (r << 9), bb = flat >> 8, ii = flat & 255;
                act[bb * 772 + ii] = x[((size_t)(b0 + bb) * I_ + ii) * T_ + t];
            }
        }
        __syncthreads();

        f32x4 r4[8];
#pragma unroll
        for (int bq = 0; bq < 8; ++bq) {
            const f32x4* ap = (const f32x4*)(act + bq * 772 + (sl << 3));
            float s0 = 0.f, s1 = 0.f, s2 = 0.f, s3 = 0.f;
#pragma unroll
            for (int q2 = 0; q2 < 2; ++q2) {
                f32x4 a = ap[q2];
#pragma unroll
                for (int e = 0; e < 4; ++e) {
                    const float av = a[e];
                    const int kk = (q2 << 2) + e;
                    s0 += av * w_x[0][kk]; s1 += av * w_x[1][kk];
                    s2 += av * w_x[2][kk]; s3 += av * w_x[3][kk];
                }
            }
            r4[bq] = (f32x4){s0, s1, s2, s3};
        }

        if (xT && t + 1 < T_)
            xv = ((const float4*)(xT + (size_t)(t + 1) * B_ * I_ + (size_t)b0 * I_))[tid];

        if (t > 0) {
            const unsigned tgt = (unsigned)t;
            for (unsigned it = 0; it < (1u << 17); ++it) {
                unsigned v = flag_load(pflag);
                if (__all((int)(v >= tgt))) break;
                __builtin_amdgcn_s_sleep(1);
            }
        }

        {
            const float* hsrc = t ? (hbuf + (size_t)((t - 1) & 1) * BH_) : h0;
            const float* src = hsrc + (size_t)(b0 + hs_bq) * H_ + hs_off;
            f32x4 v0, v1;
            asm volatile("global_load_dwordx4 %0, %2, off sc0 sc1\n\t"
                         "global_load_dwordx4 %1, %3, off sc0 sc1\n\t"
                         "s_waitcnt vmcnt(0)"
                         : "=&v"(v0), "=&v"(v1) : "v"(src), "v"(src + 4) : "memory");
            float* dst = act + hs_bq * 772 + 256 + hs_off;
            *(f32x4*)dst = v0;
            *(f32x4*)(dst + 4) = v1;
            asm volatile("s_waitcnt lgkmcnt(0)" ::: "memory");
            __builtin_amdgcn_sched_barrier(0);
        }

#pragma unroll
        for (int bq = 0; bq < 8; ++bq) {
            const f32x4* ap = (const f32x4*)(act + bq * 772 + 256 + (sl << 4));
            float s0 = 0.f, s1 = 0.f, s2 = 0.f, s3 = 0.f;
#pragma unroll
            for (int q4 = 0; q4 < 4; ++q4) {
                f32x4 a = ap[q4];
#pragma unroll
                for (int e = 0; e < 4; ++e) {
                    const float av = a[e];
                    const int kk = (q4 << 2) + e;
                    s0 += av * w_h[0][kk]; s1 += av * w_h[1][kk];
                    s2 += av * w_h[2][kk]; s3 += av * w_h[3][kk];
                }
            }
            r4[bq] += (f32x4){s0, s1, s2, s3};
        }

        if (wv < 4) {
#pragma unroll
            for (int bq = 0; bq < 8; ++bq) redA[sl * 133 + bq * 16 + jl] = r4[bq];
        }
        __syncthreads();
        f32x4 acc = redA[(qq * 4 + 0) * 133 + pr] + redA[(qq * 4 + 1) * 133 + pr]
                  + redA[(qq * 4 + 2) * 133 + pr] + redA[(qq * 4 + 3) * 133 + pr];
        __syncthreads();
        if (wv >= 4) {
#pragma unroll
            for (int bq = 0; bq < 8; ++bq) redA[(sl - 16) * 133 + bq * 16 + jl] = r4[bq];
        }
        __syncthreads();
        acc += redA[(qq * 4 + 0) * 133 + pr] + redA[(qq * 4 + 1) * 133 + pr]
             + redA[(qq * 4 + 2) * 133 + pr] + redA[(qq * 4 + 3) * 133 + pr];
        __syncthreads();
        red2[qq * 133 + pr] = acc;
        __syncthreads();

        if (tid < 128) {
            f32x4 G = red2[0 * 133 + tid] + red2[1 * 133 + tid]
                    + red2[2 * 133 + tid] + red2[3 * 133 + tid] + bias4;
            float ig = sigm(G[0]), fg = sigm(G[1]), gg = tanhf(G[2]), og = sigm(G[3]);
            c = fg * c + ig * gg;
            float hv = og * tanhf(c);
            hsh[tid] = hv;
            enc[((size_t)fb * H_ + fj) * T_ + t] = hv;
            if (t == T_ - 1) out[(size_t)fb * H_ + fj] = hv;
        }

        if (t != T_ - 1) {
            __syncthreads();
            if (tid < 32) {
                int bq = tid >> 2, q4 = tid & 3;
                f32x4 v = *(const f32x4*)(hsh + bq * 16 + q4 * 4);
                float* dst = hbuf + (size_t)(t & 1) * BH_
                           + (size_t)(b0 + bq) * H_ + j0 + q4 * 4;
                asm volatile("global_store_dwordx4 %0, %1, off sc0 sc1"
                             :: "v"(dst), "v"(v) : "memory");
            }
            if (wv == 0) {
                asm volatile("s_waitcnt vmcnt(0)" ::: "memory");
                if (tid == 0) flag_store(myflag, (unsigned)(t + 1));
            }
        }
    }
}

extern "C" void kernel_launch(void* const* d_in, const int* in_sizes, int n_in,
                              void* d_out, int out_size, void* d_ws, size_t ws_size,
                              hipStream_t stream)
{
    (void)in_sizes; (void)n_in; (void)out_size;
    const float* x   = (const float*)d_in[0];
    const float* Wih = (const float*)d_in[1];
    const float* Whh = (const float*)d_in[2];
    const float* bih = (const float*)d_in[3];
    const float* bhh = (const float*)d_in[4];
    const float* h0  = (const float*)d_in[5];
    const float* c0  = (const float*)d_in[6];
    float* out  = (float*)d_out;
    float* hbuf = (float*)d_ws;
    unsigned* cnt = (unsigned*)((char*)d_ws + WS_CNT_OFF);

    const size_t xt_bytes = (size_t)T_ * B_ * I_ * sizeof(float);
    float* xT = nullptr;
    if (ws_size >= WS_XT_OFF + xt_bytes)
        xT = (float*)((char*)d_ws + WS_XT_OFF);

    // zero flags every launch (graph-replay deterministic)
    hipMemsetAsync((char*)d_ws + WS_CNT_OFF, 0, 65536, stream);
    if (xT)
        transpose_x<<<dim3(T_ / 32, I_ / 32, B_), dim3(32, 8), 0, stream>>>(x, xT);

    void* args[] = { (void*)&x, (void*)&xT, (void*)&Wih, (void*)&Whh, (void*)&bih,
                     (void*)&bhh, (void*)&h0, (void*)&c0, (void*)&out,
                     (void*)&hbuf, (void*)&cnt };

    // deterministic host-side occupancy dispatch (pure query, capture-safe):
    // 512x256 TLP kernel needs 2 blocks/CU co-resident; otherwise r13 fallback.
    int occ = 0;
    hipError_t qe = hipOccupancyMaxActiveBlocksPerMultiprocessor(&occ, lstm_small, 256, 0);
    if (qe == hipSuccess && occ >= 2) {
        hipLaunchCooperativeKernel((void*)lstm_small, dim3(512), dim3(256), args, 0, stream);
    } else {
        hipLaunchCooperativeKernel((void*)lstm_big, dim3(256), dim3(512), args, 0, stream);
    }
}

// Round 18
// 2288.012 us; speedup vs baseline: 1.3303x; 1.0318x over previous
//
#include <hip/hip_runtime.h>

constexpr int B_ = 64, I_ = 256, H_ = 512, T_ = 512;
constexpr int BH_ = B_ * H_;

// d_ws layout: [0,256KB) hbuf ping-pong (TAGGED h) | [512KB,+33.5MB) xT
constexpr size_t WS_XT_OFF = 524288;

typedef float f32x4 __attribute__((ext_vector_type(4)));

__device__ __forceinline__ float sigm(float v) { return 1.0f / (1.0f + __expf(-v)); }

// x (B,I,T) -> xT (T,B,I), one-time
__global__ __launch_bounds__(256)
void transpose_x(const float* __restrict__ x, float* __restrict__ xT)
{
    __shared__ float tile[32][33];
    const int b  = blockIdx.z;
    const int i0 = blockIdx.y << 5;
    const int t0 = blockIdx.x << 5;
    const int lt = threadIdx.x;      // 0..31
    const int li = threadIdx.y;      // 0..7
#pragma unroll
    for (int r = 0; r < 4; ++r) {
        int i = li + (r << 3);
        tile[i][lt] = x[((size_t)b * I_ + (i0 + i)) * T_ + (t0 + lt)];
    }
    __syncthreads();
#pragma unroll
    for (int r = 0; r < 4; ++r) {
        int tt = li + (r << 3);
        xT[((size_t)(t0 + tt) * B_ + b) * I_ + (i0 + lt)] = tile[lt][tt];
    }
}

__global__ __launch_bounds__(512, 1)
void lstm_fused(const float* __restrict__ x,
                const float* __restrict__ xT,     // nullptr -> strided fallback
                const float* __restrict__ Wih,
                const float* __restrict__ Whh,
                const float* __restrict__ bih,
                const float* __restrict__ bhh,
                const float* __restrict__ h0,
                const float* __restrict__ c0,
                float* __restrict__ out,
                float* __restrict__ hbuf)
{
    // smem arena: redA[16][133] f32x4 (34048 B, aliased by red2[4][133])
    // | act[8][772] f32 (24704 B) | hsh[128] f32 (512 B)
    __shared__ char smem[59264];
    f32x4* redA = (f32x4*)smem;
    f32x4* red2 = (f32x4*)smem;                       // alias (sync-protected)
    float* act  = (float*)(smem + 34048);
    float* hsh  = (float*)(smem + 34048 + 24704);

    const int tid  = threadIdx.x;
    const int wv   = tid >> 6;
    const int lane = tid & 63;
    const int jl   = lane & 15;           // j within block's 16 / lane-in-slice-group
    const int sl   = wv * 4 + (lane >> 4);// k-slice 0..31 == producer index for h-part

    // fixed team assignment: 8 teams (b-tiles) x 32 j-blocks
    const int blk = blockIdx.x;
    const int bt  = blk >> 5;
    const int jt  = blk & 31;
    const int b0  = bt << 3;
    const int j0  = jt << 4;

    // ---- one-time: weight slices into registers ----
    // x-part: k in [sl*8, sl*8+8)  |  h-part: k-256 in [sl*16, sl*16+16)
    const int j = j0 + jl;
    float w_x[4][8];
    float w_h[4][16];
#pragma unroll
    for (int g = 0; g < 4; ++g) {
        const size_t row = (size_t)(g * H_ + j);
#pragma unroll
        for (int kk = 0; kk < 8; ++kk)  w_x[g][kk] = Wih[row * I_ + (sl << 3) + kk];
#pragma unroll
        for (int kk = 0; kk < 16; ++kk) w_h[g][kk] = Whh[row * H_ + (sl << 4) + kk];
    }

    // finalizer (tid<128) per-(b,j) state
    const int fb = b0 + (tid >> 4);
    const int fj = j0 + (tid & 15);
    float c = 0.f;
    f32x4 bias4 = {0.f, 0.f, 0.f, 0.f};
    if (tid < 128) {
        c = c0[(size_t)fb * H_ + fj];
#pragma unroll
        for (int g = 0; g < 4; ++g) bias4[g] = bih[g * H_ + fj] + bhh[g * H_ + fj];
    }

    float* enc = out + BH_;
    const int pr = tid & 127;    // reduce pair (bq = pr>>4, jl = pr&15)
    const int qq = tid >> 7;     // reduce quarter 0..3

    // h-stage role within 16-lane slice group: 8 batches x 2 halves
    const int hs_bq  = jl >> 1;
    const int hs_off = (sl << 4) + ((jl & 1) << 3);   // k-offset within h row

    // prologue: prefetch x slab for t=0
    float4 xv;
    if (xT) xv = ((const float4*)(xT + (size_t)b0 * I_))[tid];

    for (int t = 0; t < T_; ++t) {
        // ---- (a) commit x(t) ----
        if (xT) {
            *(float4*)(act + (tid >> 6) * 772 + ((tid & 63) << 2)) = xv;
        } else {
#pragma unroll
            for (int r = 0; r < 4; ++r) {
                int flat = tid + (r << 9), bb = flat >> 8, ii = flat & 255;
                act[bb * 772 + ii] = x[((size_t)(b0 + bb) * I_ + ii) * T_ + t];
            }
        }
        __syncthreads();                                   // act_x ready; prev reads done

        // ---- (b) FMA x-part (independent of h(t-1); gives producers slack) ----
        f32x4 r4[8];
#pragma unroll
        for (int bq = 0; bq < 8; ++bq) {
            const f32x4* ap = (const f32x4*)(act + bq * 772 + (sl << 3));
            float s0 = 0.f, s1 = 0.f, s2 = 0.f, s3 = 0.f;
#pragma unroll
            for (int q2 = 0; q2 < 2; ++q2) {
                f32x4 a = ap[q2];
#pragma unroll
                for (int e = 0; e < 4; ++e) {
                    const float av = a[e];
                    const int kk = (q2 << 2) + e;
                    s0 += av * w_x[0][kk]; s1 += av * w_x[1][kk];
                    s2 += av * w_x[2][kk]; s3 += av * w_x[3][kk];
                }
            }
            r4[bq] = (f32x4){s0, s1, s2, s3};
        }

        // ---- (c) prefetch x(t+1) ----
        if (xT && t + 1 < T_)
            xv = ((const float4*)(xT + (size_t)(t + 1) * B_ * I_ + (size_t)b0 * I_))[tid];

        // ---- (e) stage h(t-1): TAGGED-DATA poll (the load IS the sync; 1 RTT) ----
        {
            f32x4 v0, v1;
            if (t == 0) {
                const float* src = h0 + (size_t)(b0 + hs_bq) * H_ + hs_off;
                v0 = *(const f32x4*)src;
                v1 = *(const f32x4*)(src + 4);
            } else {
                const float* src = hbuf + (size_t)((t - 1) & 1) * BH_
                                 + (size_t)(b0 + hs_bq) * H_ + hs_off;
                const float Kc = 2.0f + 2.0f * (float)(((t - 1) >> 1) & 1);
                for (unsigned it = 0; it < 32768u; ++it) {
                    asm volatile("global_load_dwordx4 %0, %2, off sc0 sc1\n\t"
                                 "global_load_dwordx4 %1, %3, off sc0 sc1\n\t"
                                 "s_waitcnt vmcnt(0)"
                                 : "=&v"(v0), "=&v"(v1) : "v"(src), "v"(src + 4) : "memory");
                    bool ok = true;
#pragma unroll
                    for (int e = 0; e < 4; ++e) {
                        ok = ok && (fabsf(v0[e] - Kc) < 0.75f);
                        ok = ok && (fabsf(v1[e] - Kc) < 0.75f);
                    }
                    if (ok) break;
                    __builtin_amdgcn_s_sleep(1);
                }
                v0 = (v0 - Kc) * 2.0f;                    // detag (exact to 2^-22)
                v1 = (v1 - Kc) * 2.0f;
            }
            float* dst = act + hs_bq * 772 + 256 + hs_off;
            *(f32x4*)dst = v0;
            *(f32x4*)(dst + 4) = v1;
            asm volatile("s_waitcnt lgkmcnt(0)" ::: "memory");  // wave-local visibility
            __builtin_amdgcn_sched_barrier(0);
        }

        // ---- (f) FMA h-part (reads only this slice-group's 16-k window) ----
#pragma unroll
        for (int bq = 0; bq < 8; ++bq) {
            const f32x4* ap = (const f32x4*)(act + bq * 772 + 256 + (sl << 4));
            float s0 = 0.f, s1 = 0.f, s2 = 0.f, s3 = 0.f;
#pragma unroll
            for (int q4 = 0; q4 < 4; ++q4) {
                f32x4 a = ap[q4];
#pragma unroll
                for (int e = 0; e < 4; ++e) {
                    const float av = a[e];
                    const int kk = (q4 << 2) + e;
                    s0 += av * w_h[0][kk]; s1 += av * w_h[1][kk];
                    s2 += av * w_h[2][kk]; s3 += av * w_h[3][kk];
                }
            }
            r4[bq] += (f32x4){s0, s1, s2, s3};
        }

        // ---- (g) hierarchical reduce over 32 k-slices ----
        if (wv < 4) {
#pragma unroll
            for (int bq = 0; bq < 8; ++bq) redA[sl * 133 + bq * 16 + jl] = r4[bq];
        }
        __syncthreads();
        f32x4 acc = redA[(qq * 4 + 0) * 133 + pr] + redA[(qq * 4 + 1) * 133 + pr]
                  + redA[(qq * 4 + 2) * 133 + pr] + redA[(qq * 4 + 3) * 133 + pr];
        __syncthreads();
        if (wv >= 4) {
#pragma unroll
            for (int bq = 0; bq < 8; ++bq) redA[(sl - 16) * 133 + bq * 16 + jl] = r4[bq];
        }
        __syncthreads();
        acc += redA[(qq * 4 + 0) * 133 + pr] + redA[(qq * 4 + 1) * 133 + pr]
             + redA[(qq * 4 + 2) * 133 + pr] + redA[(qq * 4 + 3) * 133 + pr];
        __syncthreads();                       // protect redA reads before alias write
        red2[qq * 133 + pr] = acc;
        __syncthreads();

        // ---- (h) finalize: gates, state, enc ----
        if (tid < 128) {
            f32x4 G = red2[0 * 133 + tid] + red2[1 * 133 + tid]
                    + red2[2 * 133 + tid] + red2[3 * 133 + tid] + bias4;
            float ig = sigm(G[0]), fg = sigm(G[1]), gg = tanhf(G[2]), og = sigm(G[3]);
            c = fg * c + ig * gg;
            float hv = og * tanhf(c);
            hsh[tid] = hv;
            enc[((size_t)fb * H_ + fj) * T_ + t] = hv;          // plain cached store
            if (t == T_ - 1) out[(size_t)fb * H_ + fj] = hv;
        }

        // ---- (i) publish TAGGED h (8 full 64B lines), fire-and-forget ----
        if (t != T_ - 1) {
            __syncthreads();                   // hsh ready (also protects act reuse)
            if (tid < 32) {
                const float Kp = 2.0f + 2.0f * (float)((t >> 1) & 1);
                int bq = tid >> 2, q4 = tid & 3;
                f32x4 v = *(const f32x4*)(hsh + bq * 16 + q4 * 4);
                v = v * 0.5f + Kp;                               // tag-bias
                float* dst = hbuf + (size_t)(t & 1) * BH_
                           + (size_t)(b0 + bq) * H_ + j0 + q4 * 4;
                asm volatile("global_store_dwordx4 %0, %1, off sc0 sc1"
                             :: "v"(dst), "v"(v) : "memory");    // no drain, no flag
            }
            // WAW safety: this thread's own step-t+2 tag-poll loads issue
            // s_waitcnt vmcnt(0), draining these stores before slot reuse.
        }
    }
}

extern "C" void kernel_launch(void* const* d_in, const int* in_sizes, int n_in,
                              void* d_out, int out_size, void* d_ws, size_t ws_size,
                              hipStream_t stream)
{
    (void)in_sizes; (void)n_in; (void)out_size;
    const float* x   = (const float*)d_in[0];
    const float* Wih = (const float*)d_in[1];
    const float* Whh = (const float*)d_in[2];
    const float* bih = (const float*)d_in[3];
    const float* bhh = (const float*)d_in[4];
    const float* h0  = (const float*)d_in[5];
    const float* c0  = (const float*)d_in[6];
    float* out  = (float*)d_out;
    float* hbuf = (float*)d_ws;

    const size_t xt_bytes = (size_t)T_ * B_ * I_ * sizeof(float);
    float* xT = nullptr;
    if (ws_size >= WS_XT_OFF + xt_bytes)
        xT = (float*)((char*)d_ws + WS_XT_OFF);

    // zero hbuf every launch: stale tags from a previous replay must not validate
    hipMemsetAsync(d_ws, 0, 2 * BH_ * sizeof(float), stream);
    if (xT)
        transpose_x<<<dim3(T_ / 32, I_ / 32, B_), dim3(32, 8), 0, stream>>>(x, xT);

    void* args[] = { (void*)&x, (void*)&xT, (void*)&Wih, (void*)&Whh, (void*)&bih,
                     (void*)&bhh, (void*)&h0, (void*)&c0, (void*)&out, (void*)&hbuf };
    hipLaunchCooperativeKernel((void*)lstm_fused, dim3(256), dim3(512), args, 0, stream);
}